// Round 10
// baseline (293.854 us; speedup 1.0000x reference)
//
#include <hip/hip_runtime.h>
#include <math.h>

// Problem constants (N = 1024)
#define M_ROWS  81920            // 1024*8*10 score rows
#define NCOLS   4096
#define KPAD    48               // 45 padded to 48 (3 k-tiles of 16 for 32x32x16)
#define NCHUNK  16
#define CHUNKC  (NCOLS / NCHUNK) // 256 cols per chunk
#define CROUNDS (CHUNKC / 32)    // 8 col-rounds of 32 cols per chunk
#define FRAG    512              // halves per fragment block (64 lanes x 8)
#define ROUND6  (6 * FRAG)       // halves per round in LDS: [lo0 lo1 lo2 hi0 hi1 hi2]
#define LO_SCALE 4096.0f         // 2^12; hi ALSO scaled by 2^12 (exact pow2) so both
                                 // chains share one scale: s*4096 = ch + cl (argmax-inv)

typedef _Float16 f16x8  __attribute__((ext_vector_type(8)));
typedef float    f32x16 __attribute__((ext_vector_type(16)));

// ws layout (~18.4 MB):
//   A_pk  : _Float16[2560 * 3 * 512]  (A fragments, lane order)   7.86 MB
//   pbest : float[81920 * 16]                                     5.24 MB
//   pidx  : int  [81920 * 16]                                     5.24 MB

// ---------------------------------------------------------------------------
// Build A in MFMA-fragment order. Fragment block (rg32, kt) holds, at
// lane position (half*32 + l)*8 + j:  y(rg32*32 + l, kt*16 + half*8 + j).
// y = sign(x4·S - T - 1e-4), exactly ±1/0 in f16; zero for k >= 45.
// One thread per row; adjacent threads write adjacent 16B chunks (coalesced).
__global__ void build_A_kernel(const float* __restrict__ x,
                               const float* __restrict__ S,
                               const float* __restrict__ T,
                               _Float16* __restrict__ A_pk) {
    const int row  = blockIdx.x * 256 + threadIdx.x;
    const int pair = row / 10;
    const int c2   = row - pair * 10;
    const int a    = pair >> 3;
    const int b    = pair & 7;
    const float* xp = x + a * 480 + b * 60;
    _Float16 y[KPAD];
    #pragma unroll
    for (int j = 0; j < 45; ++j) {
        const int c = c2 * 3 + j / 15;       // constant-folded by unroll
        const int k = j % 15;
        const float x0 = xp[c * 2 + 0];
        const float x1 = xp[c * 2 + 1];
        float v = x0 * S[(c * 2 + 0) * 15 + k] + x1 * S[(c * 2 + 1) * 15 + k];
        v = v - T[c * 15 + k] - 1e-4f;
        y[j] = (v > 0.f) ? (_Float16)1.f : ((v < 0.f) ? (_Float16)-1.f : (_Float16)0.f);
    }
    #pragma unroll
    for (int j = 45; j < KPAD; ++j) y[j] = (_Float16)0.f;

    const int rg32 = row >> 5;               // fragment row-group [0, 2560)
    const int l    = row & 31;
    #pragma unroll
    for (int kt = 0; kt < 3; ++kt) {
        #pragma unroll
        for (int half = 0; half < 2; ++half) {
            f16x8 fr;
            #pragma unroll
            for (int j = 0; j < 8; ++j) fr[j] = y[kt * 16 + half * 8 + j];
            *(f16x8*)(A_pk + ((size_t)rg32 * 3 + kt) * FRAG + (half * 32 + l) * 8) = fr;
        }
    }
}

// ---------------------------------------------------------------------------
// MFMA GEMM + fused argmax with chunk's split-B RESIDENT IN LDS (48 KB).
// Each block: (1) builds its 256-col chunk's hi/lo f16 split from H directly
// into LDS in MFMA-fragment order (one pass, one __syncthreads, no build_B
// kernel, no global B traffic in the loop); (2) 4 waves x 8 rounds of
// conflict-free lane-linear ds_read_b128 + 12 MFMA + argmax epilogue.
// Compute core per R6 (best known): 2 row-tiles, two independent 3-MFMA
// chains (lo and hi, both scaled 2^12 -> combine is one v_add), czero as
// direct C operand. No __launch_bounds__ min-waves (R5: (256,4) caused an
// 847 MB scratch spill).
// 32x32 layouts (m74/m101-verified): A[m=lane&31][k=(lane>>5)*8+j];
// B[k=(lane>>5)*8+j][n=lane&31]; C/D col=lane&31, row=(e&3)+8*(e>>2)+4*(lane>>5).
__global__ __launch_bounds__(256) void score_argmax_kernel(
        const float* __restrict__ H,       // (45, 4096)
        const _Float16* __restrict__ A_pk,
        float* __restrict__ pbest,
        int*   __restrict__ pidx) {
    __shared__ _Float16 lds[CROUNDS * ROUND6];   // 8 * 3072 halves = 48 KB

    const int tid   = threadIdx.x;
    const int chunk = blockIdx.x / 320;          // block-uniform
    const int local = blockIdx.x - chunk * 320;

    // ---- stage this chunk's split-B into LDS (thread t -> col r*32+l) ----
    {
        const int r = tid >> 5;                  // round within chunk [0,8)
        const int l = tid & 31;
        const int n = chunk * CHUNKC + r * 32 + l;
        float hi[KPAD], lo[KPAD];
        #pragma unroll
        for (int k = 0; k < 45; ++k) {
            const float h = H[k * NCOLS + n];
            const _Float16 h1 = (_Float16)h;
            hi[k] = (float)h1 * LO_SCALE;        // exact pow2 scale of f16 value
            lo[k] = (h - (float)h1) * LO_SCALE;  // residual, out of f16 subnormals
        }
        #pragma unroll
        for (int k = 45; k < KPAD; ++k) { hi[k] = 0.f; lo[k] = 0.f; }
        _Float16* dst = lds + (size_t)r * ROUND6;
        #pragma unroll
        for (int kt = 0; kt < 3; ++kt) {
            f16x8 l0, l1v, h0, h1v;
            #pragma unroll
            for (int j = 0; j < 8; ++j) {
                l0[j]  = (_Float16)lo[kt * 16 + j];
                l1v[j] = (_Float16)lo[kt * 16 + 8 + j];
                h0[j]  = (_Float16)hi[kt * 16 + j];
                h1v[j] = (_Float16)hi[kt * 16 + 8 + j];
            }
            *(f16x8*)(dst + kt * FRAG + l * 8)              = l0;   // lo, half 0
            *(f16x8*)(dst + kt * FRAG + (l + 32) * 8)       = l1v;  // lo, half 1
            *(f16x8*)(dst + (3 + kt) * FRAG + l * 8)        = h0;   // hi, half 0
            *(f16x8*)(dst + (3 + kt) * FRAG + (l + 32) * 8) = h1v;  // hi, half 1
        }
    }
    __syncthreads();

    // ---- GEMM + argmax ----
    const int lane = tid & 63;
    const int l31  = lane & 31;
    const int half = lane >> 5;
    const int rg   = local * 4 + (tid >> 6);     // row-group [0,1280), 64 rows
    const int rowbase = rg * 64;

    // A fragments: 6 coalesced 1 KB loads (replaces R6's ~400 scattered loads)
    f16x8 afr[2][3];
    #pragma unroll
    for (int rt = 0; rt < 2; ++rt)
        #pragma unroll
        for (int kt = 0; kt < 3; ++kt)
            afr[rt][kt] = *(const f16x8*)(A_pk
                + ((size_t)((rowbase >> 5) + rt) * 3 + kt) * FRAG + lane * 8);

    float best[2][16];
    int   bidx[2][16];
    #pragma unroll
    for (int rt = 0; rt < 2; ++rt)
        #pragma unroll
        for (int e = 0; e < 16; ++e) { best[rt][e] = -INFINITY; bidx[rt][e] = 0; }

    f32x16 czero;
    #pragma unroll
    for (int e = 0; e < 16; ++e) czero[e] = 0.f;

    const int colbase0 = chunk * CHUNKC;
    const _Float16* bbase = lds + lane * 8;

    for (int ct = 0; ct < CROUNDS; ++ct) {
        const _Float16* bp = bbase + (size_t)ct * ROUND6;
        const f16x8 bl0 = *(const f16x8*)(bp);
        const f16x8 bl1 = *(const f16x8*)(bp + FRAG);
        const f16x8 bl2 = *(const f16x8*)(bp + 2 * FRAG);
        const f16x8 bh0 = *(const f16x8*)(bp + 3 * FRAG);
        const f16x8 bh1 = *(const f16x8*)(bp + 4 * FRAG);
        const f16x8 bh2 = *(const f16x8*)(bp + 5 * FRAG);

        const int mycol = colbase0 + ct * 32 + l31;
        #pragma unroll
        for (int rt = 0; rt < 2; ++rt) {
            // two independent 3-chains (ILP), czero as direct C operand
            f32x16 cl = __builtin_amdgcn_mfma_f32_32x32x16_f16(afr[rt][0], bl0, czero, 0, 0, 0);
            f32x16 ch = __builtin_amdgcn_mfma_f32_32x32x16_f16(afr[rt][0], bh0, czero, 0, 0, 0);
            cl = __builtin_amdgcn_mfma_f32_32x32x16_f16(afr[rt][1], bl1, cl, 0, 0, 0);
            ch = __builtin_amdgcn_mfma_f32_32x32x16_f16(afr[rt][1], bh1, ch, 0, 0, 0);
            cl = __builtin_amdgcn_mfma_f32_32x32x16_f16(afr[rt][2], bl2, cl, 0, 0, 0);
            ch = __builtin_amdgcn_mfma_f32_32x32x16_f16(afr[rt][2], bh2, ch, 0, 0, 0);
            #pragma unroll
            for (int e = 0; e < 16; ++e) {
                const float s = ch[e] + cl[e];       // score * 4096 (monotone)
                if (s > best[rt][e]) bidx[rt][e] = mycol;  // cols ascend: first idx
                best[rt][e] = fmaxf(best[rt][e], s);
            }
        }
    }

    // Cross-lane argmax over the 32 cols held by l31=0..31 (same half).
    // Tie -> smaller index (jnp.argmax first-index semantics).
    #pragma unroll
    for (int m = 1; m < 32; m <<= 1) {
        #pragma unroll
        for (int rt = 0; rt < 2; ++rt)
            #pragma unroll
            for (int e = 0; e < 16; ++e) {
                const float ov = __shfl_xor(best[rt][e], m, 64);
                const int   oi = __shfl_xor(bidx[rt][e], m, 64);
                if (ov > best[rt][e] ||
                    (ov == best[rt][e] && oi < bidx[rt][e])) {
                    best[rt][e] = ov; bidx[rt][e] = oi;
                }
            }
    }

    if (l31 == 0) {   // lanes 0 and 32 write their half's rows
        #pragma unroll
        for (int rt = 0; rt < 2; ++rt)
            #pragma unroll
            for (int e = 0; e < 16; ++e) {
                const int row = rowbase + rt * 32 + (e & 3) + 8 * (e >> 2) + 4 * half;
                pbest[(size_t)row * NCHUNK + chunk] = best[rt][e];
                pidx [(size_t)row * NCHUNK + chunk] = bidx[rt][e];
            }
    }
}

// ---------------------------------------------------------------------------
// Fold the 16 chunk partials (ascending chunk + strict > == global first-index
// argmax), gather LUT, write out (1024,8,10,2).
__global__ void reduce_lut_kernel(const float* __restrict__ pbest,
                                  const int*   __restrict__ pidx,
                                  const float* __restrict__ LUT,  // (10,4096,2)
                                  float* __restrict__ out) {
    const int row = blockIdx.x * blockDim.x + threadIdx.x;
    if (row >= M_ROWS) return;
    float best = -INFINITY;
    int   bi   = 0;
    #pragma unroll
    for (int ch = 0; ch < NCHUNK; ++ch) {
        const float bv = pbest[(size_t)row * NCHUNK + ch];
        const int   ix = pidx [(size_t)row * NCHUNK + ch];
        if (bv > best) { best = bv; bi = ix; }
    }
    const int pair = row / 10;
    const int c2   = row - pair * 10;
    const float* l = LUT + ((size_t)c2 * NCOLS + bi) * 2;
    out[row * 2 + 0] = l[0];
    out[row * 2 + 1] = l[1];
}

// ---------------------------------------------------------------------------
extern "C" void kernel_launch(void* const* d_in, const int* in_sizes, int n_in,
                              void* d_out, int out_size, void* d_ws, size_t ws_size,
                              hipStream_t stream) {
    const float* x   = (const float*)d_in[0];  // 1024*480
    const float* S   = (const float*)d_in[1];  // 30*2*15
    const float* T   = (const float*)d_in[2];  // 30*15
    const float* H   = (const float*)d_in[3];  // 45*4096
    const float* LUT = (const float*)d_in[4];  // 10*4096*2
    float* out = (float*)d_out;                // 1024*8*10*2

    _Float16* A_pk = (_Float16*)d_ws;                           // 2560*3*512
    float*  pbest = (float*)(A_pk + (size_t)2560 * 3 * FRAG);   // 81920*16
    int*    pidx  = (int*)(pbest + (size_t)M_ROWS * NCHUNK);    // 81920*16

    build_A_kernel<<<M_ROWS / 256, 256, 0, stream>>>(x, S, T, A_pk);
    // 20480 waves = 1280 row-groups(64 rows) x 16 chunks; 4 waves/block
    score_argmax_kernel<<<5120, 256, 0, stream>>>(H, A_pk, pbest, pidx);
    reduce_lut_kernel<<<M_ROWS / 256, 256, 0, stream>>>(pbest, pidx, LUT, out);
}